// Round 4
// baseline (333.122 us; speedup 1.0000x reference)
//
#include <hip/hip_runtime.h>
#include <math.h>

#define BB 2048
#define CC 10
#define HH 48
#define WW 48
#define HWSZ (HH * WW)       // 2304
#define HW4 (HWSZ / 4)       // 576 float4 groups per image
#define NPART 3              // blocks per batch element
#define NT1 192              // threads per part block (3 waves), 1 group/thread
#define GPP (HW4 / NPART)    // 192 groups per part
#define NFLD 8               // fields per (batch, part) partial record

__device__ __forceinline__ float wave_sum_f(float v) {
    #pragma unroll
    for (int off = 32; off > 0; off >>= 1) v += __shfl_down(v, off, 64);
    return v;
}
__device__ __forceinline__ int wave_sum_i(int v) {
    #pragma unroll
    for (int off = 32; off > 0; off >>= 1) v += __shfl_down(v, off, 64);
    return v;
}
__device__ __forceinline__ int wave_or_i(int v) {
    #pragma unroll
    for (int off = 32; off > 0; off >>= 1) v |= __shfl_down(v, off, 64);
    return v;
}

// 3 blocks per batch element; each thread owns exactly one float4 pixel-group.
__global__ __launch_bounds__(NT1) void part_kernel(
    const float* __restrict__ pred,      // [B,C,H,W]
    const float* __restrict__ sfeat,     // [B,256]
    const int*   __restrict__ targets,   // [B,H,W]
    const int*   __restrict__ inputs,    // [B,H,W]
    float* __restrict__ ws_part)         // [B][NPART][NFLD]
{
    __shared__ int4  tgt4[GPP + WW / 4]; // own 16 rows + next part's first row
    __shared__ float rf[4][3];
    __shared__ int   ri[4][3];

    const int blk = blockIdx.x;
    const int b   = blk / NPART;
    const int p   = blk - b * NPART;
    const int tid = threadIdx.x;

    const float4* __restrict__ pb4 = (const float4*)(pred + (size_t)b * CC * HWSZ);
    const int4*   __restrict__ tb4 = (const int4*)(targets + (size_t)b * HWSZ);
    const int4*   __restrict__ ib4 = (const int4*)(inputs + (size_t)b * HWSZ);

    const int g = p * GPP + tid;         // global float4-group index in image

    // ---- issue ALL loads up front (independent) ----
    float4 v[CC];
    #pragma unroll
    for (int c = 0; c < CC; ++c) v[c] = pb4[c * HW4 + g];
    const int4 t4 = tb4[g];
    const int4 i4 = ib4[g];
    int4 bnd = make_int4(0, 0, 0, 0);
    const bool has_bnd = (p < NPART - 1) && (tid < WW / 4);
    if (has_bnd) bnd = tb4[(p + 1) * GPP + tid];
    float sf = 0.f;
    if (p < 2 && tid < 128) sf = sfeat[(size_t)b * 256 + p * 128 + tid];

    // stage targets for neighbor lookups
    tgt4[tid] = t4;
    if (has_bnd) tgt4[GPP + tid] = bnd;
    __syncthreads();

    const int yl = tid / (WW / 4);              // 0..15
    const int xg = (tid - yl * (WW / 4)) * 4;   // 0,4,...,44
    const int yg = p * 16 + yl;                 // global row

    const int tj[4] = {t4.x, t4.y, t4.z, t4.w};
    const int ij[4] = {i4.x, i4.y, i4.z, i4.w};

    int mask = (1 << tj[0]) | (1 << tj[1]) | (1 << tj[2]) | (1 << tj[3]);
    int tr = (tj[0] != tj[1]) + (tj[1] != tj[2]) + (tj[2] != tj[3]);
    if (xg < WW - 4) {
        const int* tgts = (const int*)tgt4;
        tr += (tj[3] != tgts[(tid + 1) * 4]);
    }
    if (yg < HH - 1) {
        const int4 bl = tgt4[tid + WW / 4];
        tr += (tj[0] != bl.x) + (tj[1] != bl.y) + (tj[2] != bl.z) + (tj[3] != bl.w);
    }

    int eq = 0, cp = 0;
    float focal = 0.f, iou = 0.f, swsum = 0.f;
    const float sw_scale = 0.3f / 33.9411254969543f;
    const float dy = (float)(yg - 24);
    const float dy2 = dy * dy;

    #pragma unroll
    for (int j = 0; j < 4; ++j) {
        const int t = tj[j];
        // max / argmax / value-at-target over C=10
        float m = (&v[0].x)[j];
        int am = 0;
        float vt = (t == 0) ? m : 0.f;
        #pragma unroll
        for (int c = 1; c < CC; ++c) {
            const float vv = (&v[c].x)[j];
            if (vv > m) { m = vv; am = c; }
            if (c == t) vt = vv;
        }
        float s = 0.f;
        #pragma unroll
        for (int c = 0; c < CC; ++c) s += __expf((&v[c].x)[j] - m);
        const float lse = m + __logf(s);
        const float ce = lse - vt;
        const float pt = __expf(vt - lse);
        const float om = fmaxf(1.f - pt, 0.f);
        focal += om * om * __fsqrt_rn(om) * ce;   // om^2.5

        const bool e = (am == t);
        eq += e;
        cp += (am == ij[j]);
        const float dx = (float)(xg + j - 24);
        const float sw = 1.3f - sw_scale * __fsqrt_rn(dy2 + dx * dx);
        swsum += sw;
        if (e) iou += sw;
    }

    // ---- block reduction (3 waves) ----
    focal = wave_sum_f(focal);
    iou   = wave_sum_f(iou);
    swsum = wave_sum_f(swsum);
    sf    = wave_sum_f(sf);
    eq    = wave_sum_i(eq);
    cp    = wave_sum_i(cp);
    tr    = wave_sum_i(tr);
    mask  = wave_or_i(mask);

    const int wv = tid >> 6;
    if ((tid & 63) == 0) {
        rf[0][wv] = focal; rf[1][wv] = iou; rf[2][wv] = swsum; rf[3][wv] = sf;
        ri[0][wv] = eq;    ri[1][wv] = cp;  ri[2][wv] = tr;    ri[3][wv] = mask;
    }
    __syncthreads();
    if (tid == 0) {
        float F = 0.f, I = 0.f, S = 0.f, SF = 0.f;
        int EQ = 0, CP = 0, TR = 0, MK = 0;
        #pragma unroll
        for (int i = 0; i < 3; ++i) {
            F += rf[0][i]; I += rf[1][i]; S += rf[2][i]; SF += rf[3][i];
            EQ += ri[0][i]; CP += ri[1][i]; TR += ri[2][i]; MK |= ri[3][i];
        }
        float* q = ws_part + (size_t)(b * NPART + p) * NFLD;
        int* qi = (int*)q;
        q[0] = F; q[1] = I; q[2] = S; q[3] = SF;
        qi[4] = EQ; qi[5] = CP; qi[6] = TR; qi[7] = MK;
    }
}

__global__ __launch_bounds__(1024) void finalize_kernel(
    const float* __restrict__ ws_part,   // [B][NPART][NFLD]
    const float* __restrict__ planning,
    const float* __restrict__ reasoning,
    float* __restrict__ out)
{
    __shared__ float rf[6][16];
    const int tid = threadIdx.x;

    float F = 0.f, U = 0.f, Cv = 0.f, S = 0.f, P = 0.f, R = 0.f;
    for (int b = tid; b < BB; b += 1024) {
        float f = 0.f, io = 0.f, sw = 0.f, sfs = 0.f;
        int eq = 0, cp = 0, tr = 0, mk = 0;
        #pragma unroll
        for (int p = 0; p < NPART; ++p) {
            const float* q = ws_part + (size_t)(b * NPART + p) * NFLD;
            const int* qi = (const int*)q;
            f += q[0]; io += q[1]; sw += q[2]; sfs += q[3];
            eq += qi[4]; cp += qi[5]; tr += qi[6]; mk |= qi[7];
        }
        const float w = ((__popc(mk) > 4) ? 1.3f : 1.0f) * ((tr > WW) ? 1.2f : 1.0f);
        F += f * w;
        const float strict = (eq == HWSZ) ? 1.f : 0.f;
        U += 0.85f * (io / sw) + 0.15f * strict;
        Cv += (cp == HWSZ) ? 1.f : 0.f;
        S += sfs;
        P += planning[b];
        R += reasoning[b];
    }

    F = wave_sum_f(F); U = wave_sum_f(U); Cv = wave_sum_f(Cv);
    S = wave_sum_f(S); P = wave_sum_f(P); R = wave_sum_f(R);
    const int wv = tid >> 6;
    if ((tid & 63) == 0) {
        rf[0][wv] = F; rf[1][wv] = U; rf[2][wv] = Cv;
        rf[3][wv] = S; rf[4][wv] = P; rf[5][wv] = R;
    }
    __syncthreads();
    if (tid == 0) {
        float Ft = 0.f, Ut = 0.f, Ct = 0.f, St = 0.f, Pt = 0.f, Rt = 0.f;
        #pragma unroll
        for (int i = 0; i < 16; ++i) {
            Ft += rf[0][i]; Ut += rf[1][i]; Ct += rf[2][i];
            St += rf[3][i]; Pt += rf[4][i]; Rt += rf[5][i];
        }
        const float focal = Ft / (float)(BB * HWSZ);
        const float ut_mean = Ut / (float)BB;
        const float exact_bonus = fmaxf(-ut_mean * 5.0f, -5.0f);
        const float transform_penalty = (Ct / (float)BB) * 0.5f;
        const float sf_mean = St / (float)(BB * 256);
        const float creativity = (1.0f / (1.0f + __expf(-sf_mean))) * 0.1f;
        const float strategic = (Pt / (float)BB) * 0.1f;
        const float multi = (Rt / (float)BB) * 0.1f;
        const float complexity = ut_mean * ((float)HWSZ / 1225.0f) * 0.1f;
        float total = focal + transform_penalty + exact_bonus
                    - creativity - strategic - multi - complexity;
        if (isnan(total) || isinf(total)) total = fminf(focal, 10.0f);
        out[0] = total;
    }
}

extern "C" void kernel_launch(void* const* d_in, const int* in_sizes, int n_in,
                              void* d_out, int out_size, void* d_ws, size_t ws_size,
                              hipStream_t stream) {
    const float* pred      = (const float*)d_in[0];
    const float* sfeat     = (const float*)d_in[1];
    const float* planning  = (const float*)d_in[2];
    const float* reasoning = (const float*)d_in[3];
    const int*   targets   = (const int*)d_in[4];
    const int*   inputs    = (const int*)d_in[5];
    float* out = (float*)d_out;
    float* ws_part = (float*)d_ws;       // [BB][NPART][NFLD] = 192 KiB

    // MEASUREMENT ROUND: launch the (idempotent) part kernel TWICE.
    // The second launch overwrites ws_part with identical values, so the
    // result is unchanged; dur_us(R4) - dur_us(R3) == one part_kernel
    // duration, which the top-5 profile cannot show us (all slots are
    // harness fills at ~110 us).
    part_kernel<<<BB * NPART, NT1, 0, stream>>>(
        pred, sfeat, targets, inputs, ws_part);
    part_kernel<<<BB * NPART, NT1, 0, stream>>>(
        pred, sfeat, targets, inputs, ws_part);
    finalize_kernel<<<1, 1024, 0, stream>>>(
        ws_part, planning, reasoning, out);
}

// Round 5
// 296.705 us; speedup vs baseline: 1.1227x; 1.1227x over previous
//
#include <hip/hip_runtime.h>
#include <math.h>

#define BB 2048
#define CC 10
#define HH 48
#define WW 48
#define HWSZ (HH * WW)       // 2304
#define HW4 (HWSZ / 4)       // 576 float4 groups per image
#define NPART 3              // blocks per batch element
#define NT1 192              // threads per part block (3 waves), 1 group/thread
#define GPP (HW4 / NPART)    // 192 groups per part
#define NFLD 8               // fields per (batch, part) partial record

// R4 measurement: one part_kernel launch == 35.4 us (dur_us 297.7 -> 333.1
// with a duplicated launch), vs a 229 MB / 6.5 TB/s ~= 35-36 us mandatory
// HBM-traffic floor. The kernel is AT the memory roofline; remaining dur_us
// is harness overhead (720 MiB ws re-poison at ~110 us + input restores).

__device__ __forceinline__ float wave_sum_f(float v) {
    #pragma unroll
    for (int off = 32; off > 0; off >>= 1) v += __shfl_down(v, off, 64);
    return v;
}
__device__ __forceinline__ int wave_sum_i(int v) {
    #pragma unroll
    for (int off = 32; off > 0; off >>= 1) v += __shfl_down(v, off, 64);
    return v;
}
__device__ __forceinline__ int wave_or_i(int v) {
    #pragma unroll
    for (int off = 32; off > 0; off >>= 1) v |= __shfl_down(v, off, 64);
    return v;
}

// 3 blocks per batch element; each thread owns exactly one float4 pixel-group.
__global__ __launch_bounds__(NT1) void part_kernel(
    const float* __restrict__ pred,      // [B,C,H,W]
    const float* __restrict__ sfeat,     // [B,256]
    const int*   __restrict__ targets,   // [B,H,W]
    const int*   __restrict__ inputs,    // [B,H,W]
    float* __restrict__ ws_part)         // [B][NPART][NFLD]
{
    __shared__ int4  tgt4[GPP + WW / 4]; // own 16 rows + next part's first row
    __shared__ float rf[4][3];
    __shared__ int   ri[4][3];

    const int blk = blockIdx.x;
    const int b   = blk / NPART;
    const int p   = blk - b * NPART;
    const int tid = threadIdx.x;

    const float4* __restrict__ pb4 = (const float4*)(pred + (size_t)b * CC * HWSZ);
    const int4*   __restrict__ tb4 = (const int4*)(targets + (size_t)b * HWSZ);
    const int4*   __restrict__ ib4 = (const int4*)(inputs + (size_t)b * HWSZ);

    const int g = p * GPP + tid;         // global float4-group index in image

    // ---- issue ALL loads up front (independent) ----
    float4 v[CC];
    #pragma unroll
    for (int c = 0; c < CC; ++c) v[c] = pb4[c * HW4 + g];
    const int4 t4 = tb4[g];
    const int4 i4 = ib4[g];
    int4 bnd = make_int4(0, 0, 0, 0);
    const bool has_bnd = (p < NPART - 1) && (tid < WW / 4);
    if (has_bnd) bnd = tb4[(p + 1) * GPP + tid];
    float sf = 0.f;
    if (p < 2 && tid < 128) sf = sfeat[(size_t)b * 256 + p * 128 + tid];

    // stage targets for neighbor lookups
    tgt4[tid] = t4;
    if (has_bnd) tgt4[GPP + tid] = bnd;
    __syncthreads();

    const int yl = tid / (WW / 4);              // 0..15
    const int xg = (tid - yl * (WW / 4)) * 4;   // 0,4,...,44
    const int yg = p * 16 + yl;                 // global row

    const int tj[4] = {t4.x, t4.y, t4.z, t4.w};
    const int ij[4] = {i4.x, i4.y, i4.z, i4.w};

    int mask = (1 << tj[0]) | (1 << tj[1]) | (1 << tj[2]) | (1 << tj[3]);
    int tr = (tj[0] != tj[1]) + (tj[1] != tj[2]) + (tj[2] != tj[3]);
    if (xg < WW - 4) {
        const int* tgts = (const int*)tgt4;
        tr += (tj[3] != tgts[(tid + 1) * 4]);
    }
    if (yg < HH - 1) {
        const int4 bl = tgt4[tid + WW / 4];
        tr += (tj[0] != bl.x) + (tj[1] != bl.y) + (tj[2] != bl.z) + (tj[3] != bl.w);
    }

    int eq = 0, cp = 0;
    float focal = 0.f, iou = 0.f, swsum = 0.f;
    const float sw_scale = 0.3f / 33.9411254969543f;
    const float dy = (float)(yg - 24);
    const float dy2 = dy * dy;

    #pragma unroll
    for (int j = 0; j < 4; ++j) {
        const int t = tj[j];
        // max / argmax / value-at-target over C=10
        float m = (&v[0].x)[j];
        int am = 0;
        float vt = (t == 0) ? m : 0.f;
        #pragma unroll
        for (int c = 1; c < CC; ++c) {
            const float vv = (&v[c].x)[j];
            if (vv > m) { m = vv; am = c; }
            if (c == t) vt = vv;
        }
        float s = 0.f;
        #pragma unroll
        for (int c = 0; c < CC; ++c) s += __expf((&v[c].x)[j] - m);
        const float lse = m + __logf(s);
        const float ce = lse - vt;
        const float pt = __expf(vt - lse);
        const float om = fmaxf(1.f - pt, 0.f);
        focal += om * om * __fsqrt_rn(om) * ce;   // om^2.5

        const bool e = (am == t);
        eq += e;
        cp += (am == ij[j]);
        const float dx = (float)(xg + j - 24);
        const float sw = 1.3f - sw_scale * __fsqrt_rn(dy2 + dx * dx);
        swsum += sw;
        if (e) iou += sw;
    }

    // ---- block reduction (3 waves) ----
    focal = wave_sum_f(focal);
    iou   = wave_sum_f(iou);
    swsum = wave_sum_f(swsum);
    sf    = wave_sum_f(sf);
    eq    = wave_sum_i(eq);
    cp    = wave_sum_i(cp);
    tr    = wave_sum_i(tr);
    mask  = wave_or_i(mask);

    const int wv = tid >> 6;
    if ((tid & 63) == 0) {
        rf[0][wv] = focal; rf[1][wv] = iou; rf[2][wv] = swsum; rf[3][wv] = sf;
        ri[0][wv] = eq;    ri[1][wv] = cp;  ri[2][wv] = tr;    ri[3][wv] = mask;
    }
    __syncthreads();
    if (tid == 0) {
        float F = 0.f, I = 0.f, S = 0.f, SF = 0.f;
        int EQ = 0, CP = 0, TR = 0, MK = 0;
        #pragma unroll
        for (int i = 0; i < 3; ++i) {
            F += rf[0][i]; I += rf[1][i]; S += rf[2][i]; SF += rf[3][i];
            EQ += ri[0][i]; CP += ri[1][i]; TR += ri[2][i]; MK |= ri[3][i];
        }
        float* q = ws_part + (size_t)(b * NPART + p) * NFLD;
        int* qi = (int*)q;
        q[0] = F; q[1] = I; q[2] = S; q[3] = SF;
        qi[4] = EQ; qi[5] = CP; qi[6] = TR; qi[7] = MK;
    }
}

__global__ __launch_bounds__(1024) void finalize_kernel(
    const float* __restrict__ ws_part,   // [B][NPART][NFLD]
    const float* __restrict__ planning,
    const float* __restrict__ reasoning,
    float* __restrict__ out)
{
    __shared__ float rf[6][16];
    const int tid = threadIdx.x;

    float F = 0.f, U = 0.f, Cv = 0.f, S = 0.f, P = 0.f, R = 0.f;
    for (int b = tid; b < BB; b += 1024) {
        float f = 0.f, io = 0.f, sw = 0.f, sfs = 0.f;
        int eq = 0, cp = 0, tr = 0, mk = 0;
        #pragma unroll
        for (int p = 0; p < NPART; ++p) {
            const float* q = ws_part + (size_t)(b * NPART + p) * NFLD;
            const int* qi = (const int*)q;
            f += q[0]; io += q[1]; sw += q[2]; sfs += q[3];
            eq += qi[4]; cp += qi[5]; tr += qi[6]; mk |= qi[7];
        }
        const float w = ((__popc(mk) > 4) ? 1.3f : 1.0f) * ((tr > WW) ? 1.2f : 1.0f);
        F += f * w;
        const float strict = (eq == HWSZ) ? 1.f : 0.f;
        U += 0.85f * (io / sw) + 0.15f * strict;
        Cv += (cp == HWSZ) ? 1.f : 0.f;
        S += sfs;
        P += planning[b];
        R += reasoning[b];
    }

    F = wave_sum_f(F); U = wave_sum_f(U); Cv = wave_sum_f(Cv);
    S = wave_sum_f(S); P = wave_sum_f(P); R = wave_sum_f(R);
    const int wv = tid >> 6;
    if ((tid & 63) == 0) {
        rf[0][wv] = F; rf[1][wv] = U; rf[2][wv] = Cv;
        rf[3][wv] = S; rf[4][wv] = P; rf[5][wv] = R;
    }
    __syncthreads();
    if (tid == 0) {
        float Ft = 0.f, Ut = 0.f, Ct = 0.f, St = 0.f, Pt = 0.f, Rt = 0.f;
        #pragma unroll
        for (int i = 0; i < 16; ++i) {
            Ft += rf[0][i]; Ut += rf[1][i]; Ct += rf[2][i];
            St += rf[3][i]; Pt += rf[4][i]; Rt += rf[5][i];
        }
        const float focal = Ft / (float)(BB * HWSZ);
        const float ut_mean = Ut / (float)BB;
        const float exact_bonus = fmaxf(-ut_mean * 5.0f, -5.0f);
        const float transform_penalty = (Ct / (float)BB) * 0.5f;
        const float sf_mean = St / (float)(BB * 256);
        const float creativity = (1.0f / (1.0f + __expf(-sf_mean))) * 0.1f;
        const float strategic = (Pt / (float)BB) * 0.1f;
        const float multi = (Rt / (float)BB) * 0.1f;
        const float complexity = ut_mean * ((float)HWSZ / 1225.0f) * 0.1f;
        float total = focal + transform_penalty + exact_bonus
                    - creativity - strategic - multi - complexity;
        if (isnan(total) || isinf(total)) total = fminf(focal, 10.0f);
        out[0] = total;
    }
}

extern "C" void kernel_launch(void* const* d_in, const int* in_sizes, int n_in,
                              void* d_out, int out_size, void* d_ws, size_t ws_size,
                              hipStream_t stream) {
    const float* pred      = (const float*)d_in[0];
    const float* sfeat     = (const float*)d_in[1];
    const float* planning  = (const float*)d_in[2];
    const float* reasoning = (const float*)d_in[3];
    const int*   targets   = (const int*)d_in[4];
    const int*   inputs    = (const int*)d_in[5];
    float* out = (float*)d_out;
    float* ws_part = (float*)d_ws;       // [BB][NPART][NFLD] = 192 KiB

    part_kernel<<<BB * NPART, NT1, 0, stream>>>(
        pred, sfeat, targets, inputs, ws_part);
    finalize_kernel<<<1, 1024, 0, stream>>>(
        ws_part, planning, reasoning, out);
}